// Round 4
// baseline (98.110 us; speedup 1.0000x reference)
//
#include <hip/hip_runtime.h>

#define NT 128
#define TOK 128

#define GL16(gp, lp) __builtin_amdgcn_global_load_lds( \
    (const __attribute__((address_space(1))) void*)(gp), \
    (__attribute__((address_space(3))) void*)(lp), 16, 0, 0)
#define GL4(gp, lp) __builtin_amdgcn_global_load_lds( \
    (const __attribute__((address_space(1))) void*)(gp), \
    (__attribute__((address_space(3))) void*)(lp), 4, 0, 0)
#define WAITVM(N) asm volatile("s_waitcnt vmcnt(" #N ")" ::: "memory")
// Barrier with DS-queue drain but NO vmcnt drain: keeps counted prefetch alive,
// makes ds_write/ds_read results visible across waves (raw s_barrier alone races).
#define BARL() do { \
    asm volatile("s_waitcnt lgkmcnt(0)" ::: "memory"); \
    __builtin_amdgcn_sched_barrier(0); \
    __builtin_amdgcn_s_barrier(); \
    __builtin_amdgcn_sched_barrier(0); \
} while (0)

// 1440 float4 -> LDS, exactly 12 GL16 issues per wave (11 full + 1 sixteen-lane
// partial) so per-wave vmcnt bookkeeping is uniform.
__device__ __forceinline__ void stage45(const float* __restrict__ g, float* lds,
                                        int tid, int wid, int lane) {
    const float4* g4 = (const float4*)g;
    #pragma unroll
    for (int it = 0; it < 11; ++it)
        GL16(g4 + it * 128 + tid, lds + it * 512 + wid * 256);
    if (lane < 16)                                   // 32 f4 remainder, 16 lanes/wave
        GL16(g4 + 1408 + wid * 16 + lane, lds + 5632 + wid * 64);
}

// One dist chunk = row c of D for all 128 tokens = 1920 floats, 15 GL4/wave.
// element m = it*128 + tid ; token = m/15, j = m%15 ; off = token*225 + j.
__device__ __forceinline__ void stage_chunk(const float* __restrict__ dchunk, float* slot,
                                            int off0, int j0, int wid) {
    int off = off0, j = j0;
    #pragma unroll
    for (int it = 0; it < 15; ++it) {
        GL4(dchunk + off, slot + it * 128 + wid * 64);
        j += 8;
        bool w = (j >= 15);
        j -= w ? 15 : 0;
        off += w ? 2018 : 1808;     // 9*225-7 : 8*225+8
    }
}

// dst[h][n] = (|.|) sum_d row[d*15+n] * w[h*3+d] + bb[h]   (stride-45/lane: 2-way bank, free)
template <bool ABS>
__device__ __forceinline__ void projr(const float* row, const float w[9], const float bb[3],
                                      float dst[3][15]) {
    #pragma unroll
    for (int n = 0; n < 15; ++n) {
        float x0 = row[n], x1 = row[15 + n], x2 = row[30 + n];
        #pragma unroll
        for (int h = 0; h < 3; ++h) {
            float y = fmaf(x2, w[h*3+2], fmaf(x1, w[h*3+1], fmaf(x0, w[h*3+0], bb[h])));
            dst[h][n] = ABS ? fabsf(y) : y;
        }
    }
}

// Phase c: counted-wait chunk c, barrier (DS-drained), accumulate row c, issue chunk c+3.
// Slot (c+3)&3 == (c-1)&3: its ds_reads finished before this phase's BARL (lgkmcnt drained).
#define PHASE(c, WN) do { \
    WAITVM(WN); BARL(); \
    { const float* sl = ring + ((c) & 3) * 1920 + tid * 15; \
      _Pragma("unroll") \
      for (int jj = 0; jj < 15; ++jj) { \
        float dd = sl[jj]; \
        concat[(c)*3 + 0] = fmaf(dd, vv[0][jj], concat[(c)*3 + 0]); \
        concat[(c)*3 + 1] = fmaf(dd, vv[1][jj], concat[(c)*3 + 1]); \
        concat[(c)*3 + 2] = fmaf(dd, vv[2][jj], concat[(c)*3 + 2]); \
      } } \
    if ((c) <= 11) stage_chunk(dbase + ((c)+3)*15, ring + (((c)+3)&3)*1920, off0, j0, wid); \
} while (0)

__global__ __launch_bounds__(NT, 2) void mha_spatial_kernel(
    const float* __restrict__ q, const float* __restrict__ k, const float* __restrict__ v,
    const float* __restrict__ dist,
    const float* __restrict__ Wq, const float* __restrict__ bq,
    const float* __restrict__ Wk, const float* __restrict__ bk,
    const float* __restrict__ Wv, const float* __restrict__ bv,
    const float* __restrict__ Wo, const float* __restrict__ bo,
    float* __restrict__ out)
{
    __shared__ __align__(16) float region0[5760];   // 22.5 KB: q -> v -> out staging
    __shared__ __align__(16) float ring[7680];      // 30 KB: k (slots 0-2), then dist ring-4
    const int tid  = threadIdx.x;
    const int lane = tid & 63;
    const int wid  = tid >> 6;
    const int base = blockIdx.x * TOK;

    // Preload tiny projection weights into regs BEFORE any counted GL issue, then
    // drain, so the vmcnt arithmetic below is exact.
    float wq[9], wk[9], wv[9], bqv[3], bkv[3], bvv[3];
    #pragma unroll
    for (int i = 0; i < 9; ++i) { wq[i] = Wq[i]; wk[i] = Wk[i]; wv[i] = Wv[i]; }
    #pragma unroll
    for (int i = 0; i < 3; ++i) { bqv[i] = bq[i]; bkv[i] = bk[i]; bvv[i] = bv[i]; }
    WAITVM(0);

    stage45(q + (size_t)base * 45, region0, tid, wid, lane);   // 12 issues
    stage45(k + (size_t)base * 45, ring,    tid, wid, lane);   // 12 issues
    WAITVM(12); BARL();                       // q landed (k's 12 in flight)

    float a[3][15], b[3][15], vv[3][15];
    projr<true>(region0 + tid * 45, wq, bqv, a);
    BARL();                                   // projr reads drained -> region0 free
    stage45(v + (size_t)base * 45, region0, tid, wid, lane);   // 12 issues (out: k12+v12)
    WAITVM(12); BARL();                       // k landed (v in flight)
    projr<true>(ring + tid * 45, wk, bkv, b);
    BARL();                                   // ring free

    const float* dbase = dist + (size_t)base * 225;
    const int tok0 = tid / 15, j0 = tid - tok0 * 15;
    const int off0 = tok0 * 225 + j0;
    stage_chunk(dbase +  0, ring +    0, off0, j0, wid);   // c0
    stage_chunk(dbase + 15, ring + 1920, off0, j0, wid);   // c1
    stage_chunk(dbase + 30, ring + 3840, off0, j0, wid);   // c2
    WAITVM(45); BARL();                       // v landed (45 dist in flight)
    projr<false>(region0 + tid * 45, wv, bvv, vv);

    // ---- softmax + PV in registers (overlaps c0-c2 flight) ----
    // scores = a_i*b_j >= 0 => max = amax*bmax. Fold log2(e) into a: exp -> exp2.
    const float LOG2E = 1.4426950408889634f;
    #pragma unroll
    for (int h = 0; h < 3; ++h)
        #pragma unroll
        for (int n = 0; n < 15; ++n) a[h][n] *= LOG2E;

    float concat[45];                         // concat[n*3+h]
    #pragma unroll
    for (int h = 0; h < 3; ++h) {
        float amax = a[h][0], bmax = b[h][0];
        #pragma unroll
        for (int n = 1; n < 15; ++n) { amax = fmaxf(amax, a[h][n]); bmax = fmaxf(bmax, b[h][n]); }
        const float mm2 = amax * bmax;        // = max(score)*log2e
        float Z = 0.f, pv[15];
        #pragma unroll
        for (int i = 0; i < 15; ++i) pv[i] = 0.f;
        #pragma unroll
        for (int i = 0; i < 15; ++i)
            #pragma unroll
            for (int j = 0; j < 15; ++j) {
                float t = exp2f(fmaf(a[h][i], b[h][j], -mm2));
                Z += t;
                pv[i] = fmaf(t, vv[h][j], pv[i]);
            }
        const float rz = 1.f / Z;
        #pragma unroll
        for (int i = 0; i < 15; ++i) concat[i*3 + h] = pv[i] * rz;
    }
    #pragma unroll
    for (int h = 0; h < 3; ++h)
        #pragma unroll
        for (int j = 0; j < 15; ++j) vv[h][j] *= 2.f;   // fold 2*distances into v

    // ---- 15-row dist stream, ring-4, prefetch distance 3, counted vmcnt ----
    PHASE( 0, 30); PHASE( 1, 30); PHASE( 2, 30); PHASE( 3, 30);
    PHASE( 4, 30); PHASE( 5, 30); PHASE( 6, 30); PHASE( 7, 30);
    PHASE( 8, 30); PHASE( 9, 30); PHASE(10, 30); PHASE(11, 30);
    PHASE(12, 30); PHASE(13, 15); PHASE(14, 0);

    // ---- output projection: Wo/bo via uniform (scalar) loads, no LDS staging ----
    #pragma unroll 3
    for (int o = 0; o < 45; ++o) {
        float acc = bo[o];
        const float* wr = Wo + o * 45;        // uniform address -> s_load + SGPR-src fma
        #pragma unroll
        for (int cc = 0; cc < 45; ++cc) acc = fmaf(concat[cc], wr[cc], acc);
        region0[tid * 45 + o] = acc;
    }
    BARL();                                   // ds_writes visible to all waves
    {
        float4* o4 = (float4*)(out + (size_t)base * 45);
        const float4* s4 = (const float4*)region0;
        #pragma unroll
        for (int it = 0; it < 12; ++it) {
            int idx = it * 128 + tid;
            if (idx < 1440) o4[idx] = s4[idx];
        }
    }
}

extern "C" void kernel_launch(void* const* d_in, const int* in_sizes, int n_in,
                              void* d_out, int out_size, void* d_ws, size_t ws_size,
                              hipStream_t stream) {
    const float* q  = (const float*)d_in[0];
    const float* k  = (const float*)d_in[1];
    const float* v  = (const float*)d_in[2];
    const float* ds = (const float*)d_in[3];
    const float* Wq = (const float*)d_in[5];
    const float* bq = (const float*)d_in[6];
    const float* Wk = (const float*)d_in[7];
    const float* bk = (const float*)d_in[8];
    const float* Wv = (const float*)d_in[9];
    const float* bv = (const float*)d_in[10];
    const float* Wo = (const float*)d_in[11];
    const float* bo = (const float*)d_in[12];
    float* out = (float*)d_out;

    // att_val = zeros(4096) at the tail of d_out
    hipMemsetAsync(out + (size_t)32 * 4096 * 45, 0, 4096 * sizeof(float), stream);

    mha_spatial_kernel<<<dim3((32 * 4096) / TOK), dim3(NT), 0, stream>>>(
        q, k, v, ds, Wq, bq, Wk, bk, Wv, bv, Wo, bo, out);
}

// Round 5
// 82.021 us; speedup vs baseline: 1.1962x; 1.1962x over previous
//
#include <hip/hip_runtime.h>

#define NT 64
#define TOK 64

#define GL16(gp, lp) __builtin_amdgcn_global_load_lds( \
    (const __attribute__((address_space(1))) void*)(gp), \
    (__attribute__((address_space(3))) void*)(lp), 16, 0, 0)
#define GL4(gp, lp) __builtin_amdgcn_global_load_lds( \
    (const __attribute__((address_space(1))) void*)(gp), \
    (__attribute__((address_space(3))) void*)(lp), 4, 0, 0)
#define WAITVM(N) asm volatile("s_waitcnt vmcnt(" #N ")" ::: "memory")
// Same-wave DS drain + scheduling fence (rule #18) before overwriting a slot we just read.
#define WAITLG() do { \
    asm volatile("s_waitcnt lgkmcnt(0)" ::: "memory"); \
    __builtin_amdgcn_sched_barrier(0); \
} while (0)

#if defined(__has_builtin)
# if __has_builtin(__builtin_amdgcn_exp2f)
#  define EXP2F(x) __builtin_amdgcn_exp2f(x)
# else
#  define EXP2F(x) exp2f(x)
# endif
#else
# define EXP2F(x) exp2f(x)
#endif

// 64 tokens x 45 floats = 720 float4 -> LDS, 12 GL16 per wave (11 full + 16-lane partial).
__device__ __forceinline__ void stage45(const float* __restrict__ g, float* lds, int lane) {
    const float4* g4 = (const float4*)g;
    #pragma unroll
    for (int it = 0; it < 11; ++it)
        GL16(g4 + it * 64 + lane, lds + it * 256);
    if (lane < 16) GL16(g4 + 704 + lane, lds + 2816);
}

// One dist row r for this wave's 64 tokens = 960 floats, 15 GL4.
// m = it*64 + lane ; tok = m/15 ; j = m%15 ; off = tok*225 + j (dr has r*15 folded in).
__device__ __forceinline__ void stage_row(const float* __restrict__ dr, float* slot,
                                          int off0, int j0) {
    int off = off0, j = j0;
    #pragma unroll
    for (int it = 0; it < 15; ++it) {
        GL4(dr + off, slot + it * 64);
        j += 4;
        bool w = (j >= 15);
        j -= w ? 15 : 0;
        off += w ? 1114 : 904;      // wrap: 5*225-11 ; no-wrap: 4*225+4
    }
}

// dst[h][n] = (|.|) sum_d row[d*15+n]*w[h*3+d] + bb[h]  (stride-45/lane: 2-way bank, free)
template <bool ABS>
__device__ __forceinline__ void projr(const float* row, const float w[9], const float bb[3],
                                      float dst[3][15]) {
    #pragma unroll
    for (int n = 0; n < 15; ++n) {
        float x0 = row[n], x1 = row[15 + n], x2 = row[30 + n];
        #pragma unroll
        for (int h = 0; h < 3; ++h) {
            float y = fmaf(x2, w[h*3+2], fmaf(x1, w[h*3+1], fmaf(x0, w[h*3+0], bb[h])));
            dst[h][n] = ABS ? fabsf(y) : y;
        }
    }
}

// Phase p: counted wait for row p (oldest 15), consume slot (p+3)%6, issue row p+5
// into slot (p+8)%6 == (p+2)%6 (read at phase p-1; WAITLG re-drains as WAR insurance).
#define PHASE(p, WN) do { \
    WAITVM(WN); \
    __builtin_amdgcn_sched_barrier(0); \
    { const float* sl = ring + (((p) + 3) % 6) * 960 + lane * 15; \
      _Pragma("unroll") \
      for (int jj = 0; jj < 15; ++jj) { \
        float dd = sl[jj]; \
        concat[(p)*3 + 0] = fmaf(dd, vv[0][jj], concat[(p)*3 + 0]); \
        concat[(p)*3 + 1] = fmaf(dd, vv[1][jj], concat[(p)*3 + 1]); \
        concat[(p)*3 + 2] = fmaf(dd, vv[2][jj], concat[(p)*3 + 2]); \
      } } \
    if ((p) <= 9) { WAITLG(); stage_row(dbase + ((p)+5)*15, ring + (((p)+8)%6)*960, off0, j0); } \
} while (0)

__global__ __launch_bounds__(NT, 2) void mha_spatial_kernel(
    const float* __restrict__ q, const float* __restrict__ k, const float* __restrict__ v,
    const float* __restrict__ dist,
    const float* __restrict__ Wq, const float* __restrict__ bq,
    const float* __restrict__ Wk, const float* __restrict__ bk,
    const float* __restrict__ Wv, const float* __restrict__ bv,
    const float* __restrict__ Wo, const float* __restrict__ bo,
    float* __restrict__ out)
{
    __shared__ __align__(16) float ring[5760];   // 6 slots x 960 floats = 22.5 KB total
    const int lane = threadIdx.x;                // one wave per block
    const int base = blockIdx.x * TOK;

    // Tiny projection weights via uniform loads before any counted GL issue.
    float wq[9], wk[9], wv[9], bqv[3], bkv[3], bvv[3];
    #pragma unroll
    for (int i = 0; i < 9; ++i) { wq[i] = Wq[i]; wk[i] = Wk[i]; wv[i] = Wv[i]; }
    #pragma unroll
    for (int i = 0; i < 3; ++i) { bqv[i] = bq[i]; bkv[i] = bk[i]; bvv[i] = bv[i]; }
    WAITVM(0);

    stage45(q + (size_t)base * 45, ring,        lane);   // S0-2   [vm 12]
    stage45(k + (size_t)base * 45, ring + 2880, lane);   // S3-5   [vm 24]
    WAITVM(12);                                          // q landed

    float a[3][15], b[3][15], vv[3][15];
    projr<true>(ring + lane * 45, wq, bqv, a);
    WAITLG();
    stage45(v + (size_t)base * 45, ring, lane);          // S0-2   [vm 24]
    WAITVM(12);                                          // k landed (v in flight)
    projr<true>(ring + 2880 + lane * 45, wk, bkv, b);
    WAITLG();

    const float* dbase = dist + (size_t)base * 225;
    const int tok0 = lane / 15, j0 = lane - tok0 * 15;
    const int off0 = tok0 * 225 + j0;
    stage_row(dbase +  0, ring + 3 * 960, off0, j0);     // r0 -> S3  [vm 57]
    stage_row(dbase + 15, ring + 4 * 960, off0, j0);     // r1 -> S4
    stage_row(dbase + 30, ring + 5 * 960, off0, j0);     // r2 -> S5
    WAITVM(45);                                          // v landed
    projr<false>(ring + lane * 45, wv, bvv, vv);
    WAITLG();
    stage_row(dbase + 45, ring + 0 * 960, off0, j0);     // r3 -> S0  [vm 75]
    stage_row(dbase + 60, ring + 1 * 960, off0, j0);     // r4 -> S1

    // ---- softmax + PV in registers (5 dist rows in flight underneath) ----
    const float LOG2E = 1.4426950408889634f;
    #pragma unroll
    for (int h = 0; h < 3; ++h)
        #pragma unroll
        for (int n = 0; n < 15; ++n) a[h][n] *= LOG2E;

    float concat[45];                         // concat[n*3+h]
    #pragma unroll
    for (int h = 0; h < 3; ++h) {
        float amax = a[h][0], bmax = b[h][0];
        #pragma unroll
        for (int n = 1; n < 15; ++n) { amax = fmaxf(amax, a[h][n]); bmax = fmaxf(bmax, b[h][n]); }
        const float mm2 = amax * bmax;
        float zp[4] = {0.f, 0.f, 0.f, 0.f};   // 4-way partial sums: break the Z chain
        float pv[15];
        #pragma unroll
        for (int i = 0; i < 15; ++i) pv[i] = 0.f;
        #pragma unroll
        for (int i = 0; i < 15; ++i)
            #pragma unroll
            for (int j = 0; j < 15; ++j) {
                float t = EXP2F(fmaf(a[h][i], b[h][j], -mm2));
                zp[j & 3] += t;
                pv[i] = fmaf(t, vv[h][j], pv[i]);
            }
        const float rz = 1.f / ((zp[0] + zp[1]) + (zp[2] + zp[3]));
        #pragma unroll
        for (int i = 0; i < 15; ++i) concat[i*3 + h] = pv[i] * rz;
    }
    #pragma unroll
    for (int h = 0; h < 3; ++h)
        #pragma unroll
        for (int j = 0; j < 15; ++j) vv[h][j] *= 2.f;   // fold 2*distances into v

    // ---- 15 dist rows, 6-slot ring, prefetch distance 5, counted vmcnt ----
    PHASE( 0, 60); PHASE( 1, 60); PHASE( 2, 60); PHASE( 3, 60);
    PHASE( 4, 60); PHASE( 5, 60); PHASE( 6, 60); PHASE( 7, 60);
    PHASE( 8, 60); PHASE( 9, 60); PHASE(10, 60); PHASE(11, 45);
    PHASE(12, 30); PHASE(13, 15); PHASE(14, 0);

    // ---- output projection: Wo/bo via uniform scalar loads ----
    #pragma unroll 3
    for (int o = 0; o < 45; ++o) {
        float acc = bo[o];
        const float* wr = Wo + o * 45;        // uniform address -> s_load
        #pragma unroll
        for (int cc = 0; cc < 45; ++cc) acc = fmaf(concat[cc], wr[cc], acc);
        ring[lane * 45 + o] = acc;            // S0-2 free after phases 9-11
    }
    WAITLG();                                 // same-wave ds_writes drained
    {
        float4* o4 = (float4*)(out + (size_t)base * 45);
        const float4* s4 = (const float4*)ring;
        #pragma unroll
        for (int it = 0; it < 11; ++it) o4[it * 64 + lane] = s4[it * 64 + lane];
        if (lane < 16) o4[704 + lane] = s4[704 + lane];
    }
}

extern "C" void kernel_launch(void* const* d_in, const int* in_sizes, int n_in,
                              void* d_out, int out_size, void* d_ws, size_t ws_size,
                              hipStream_t stream) {
    const float* q  = (const float*)d_in[0];
    const float* k  = (const float*)d_in[1];
    const float* v  = (const float*)d_in[2];
    const float* ds = (const float*)d_in[3];
    const float* Wq = (const float*)d_in[5];
    const float* bq = (const float*)d_in[6];
    const float* Wk = (const float*)d_in[7];
    const float* bk = (const float*)d_in[8];
    const float* Wv = (const float*)d_in[9];
    const float* bv = (const float*)d_in[10];
    const float* Wo = (const float*)d_in[11];
    const float* bo = (const float*)d_in[12];
    float* out = (float*)d_out;

    // att_val = zeros(4096) at the tail of d_out
    hipMemsetAsync(out + (size_t)32 * 4096 * 45, 0, 4096 * sizeof(float), stream);

    mha_spatial_kernel<<<dim3((32 * 4096) / TOK), dim3(NT), 0, stream>>>(
        q, k, v, ds, Wq, bq, Wk, bk, Wv, bv, Wo, bo, out);
}

// Round 6
// 56.131 us; speedup vs baseline: 1.7479x; 1.4612x over previous
//
#include <hip/hip_runtime.h>

#define NT 64
#define TOK 64

#define GL16(gp, lp) __builtin_amdgcn_global_load_lds( \
    (const __attribute__((address_space(1))) void*)(gp), \
    (__attribute__((address_space(3))) void*)(lp), 16, 0, 0)
#define GL4(gp, lp) __builtin_amdgcn_global_load_lds( \
    (const __attribute__((address_space(1))) void*)(gp), \
    (__attribute__((address_space(3))) void*)(lp), 4, 0, 0)
#define WAITVM(N) do { \
    asm volatile("s_waitcnt vmcnt(" #N ")" ::: "memory"); \
    __builtin_amdgcn_sched_barrier(0); \
} while (0)
// Same-wave DS drain + scheduling fence (rule #18) before overwriting a slot we just read.
#define WAITLG() do { \
    asm volatile("s_waitcnt lgkmcnt(0)" ::: "memory"); \
    __builtin_amdgcn_sched_barrier(0); \
} while (0)

#if defined(__has_builtin)
# if __has_builtin(__builtin_amdgcn_exp2f)
#  define EXP2F(x) __builtin_amdgcn_exp2f(x)
# else
#  define EXP2F(x) exp2f(x)
# endif
#else
# define EXP2F(x) exp2f(x)
#endif

// 64 tokens x 45 floats = 720 float4 -> LDS, 12 GL16 per wave (11 full + 16-lane partial).
__device__ __forceinline__ void stage45(const float* __restrict__ g, float* lds, int lane) {
    const float4* g4 = (const float4*)g;
    #pragma unroll
    for (int it = 0; it < 11; ++it)
        GL16(g4 + it * 64 + lane, lds + it * 256);
    if (lane < 16) GL16(g4 + 704 + lane, lds + 2816);
}

// One dist row r for this wave's 64 tokens = 960 floats, 15 GL4.
// m = it*64 + lane ; tok = m/15 ; j = m%15 ; off = tok*225 + j (dr has r*15 folded in).
__device__ __forceinline__ void stage_row(const float* __restrict__ dr, float* slot,
                                          int off0, int j0) {
    int off = off0, j = j0;
    #pragma unroll
    for (int it = 0; it < 15; ++it) {
        GL4(dr + off, slot + it * 64);
        j += 4;
        bool w = (j >= 15);
        j -= w ? 15 : 0;
        off += w ? 1114 : 904;      // wrap: 5*225-11 ; no-wrap: 4*225+4
    }
}

// dst[h][n] = (|.|) sum_d row[d*15+n]*w[h*3+d] + bb[h]  (stride-45/lane: conflict-free)
template <bool ABS>
__device__ __forceinline__ void projr(const float* row, const float w[9], const float bb[3],
                                      float dst[3][15]) {
    #pragma unroll
    for (int n = 0; n < 15; ++n) {
        float x0 = row[n], x1 = row[15 + n], x2 = row[30 + n];
        #pragma unroll
        for (int h = 0; h < 3; ++h) {
            float y = fmaf(x2, w[h*3+2], fmaf(x1, w[h*3+1], fmaf(x0, w[h*3+0], bb[h])));
            dst[h][n] = ABS ? fabsf(y) : y;
        }
    }
}

// Phase p: counted wait for row p (slot p%3), consume, then issue row p+2 into
// slot (p+2)%3 (= slot consumed at phase p-1; WAITLG drains those ds_reads first).
#define PHASE(p, WN) do { \
    WAITVM(WN); \
    { const float* sl = buf + ((p) % 3) * 960 + lane * 15; \
      _Pragma("unroll") \
      for (int jj = 0; jj < 15; ++jj) { \
        float dd = sl[jj]; \
        concat[(p)*3 + 0] = fmaf(dd, vv[0][jj], concat[(p)*3 + 0]); \
        concat[(p)*3 + 1] = fmaf(dd, vv[1][jj], concat[(p)*3 + 1]); \
        concat[(p)*3 + 2] = fmaf(dd, vv[2][jj], concat[(p)*3 + 2]); \
      } } \
    if ((p) <= 12) { WAITLG(); stage_row(dbase + ((p)+2)*15, buf + (((p)+2)%3)*960, off0, j0); } \
} while (0)

__global__ __launch_bounds__(NT, 2) void mha_spatial_kernel(
    const float* __restrict__ q, const float* __restrict__ k, const float* __restrict__ v,
    const float* __restrict__ dist,
    const float* __restrict__ Wq, const float* __restrict__ bq,
    const float* __restrict__ Wk, const float* __restrict__ bk,
    const float* __restrict__ Wv, const float* __restrict__ bv,
    const float* __restrict__ Wo, const float* __restrict__ bo,
    float* __restrict__ out)
{
    __shared__ __align__(16) float buf[2880];    // 11.25 KB: qkv (serial) -> dist ring-3 -> out
    const int lane = threadIdx.x;                // one wave per block
    const int base = blockIdx.x * TOK;

    // Tiny projection weights via uniform (scalar) loads.
    float wq[9], wk[9], wv[9], bqv[3], bkv[3], bvv[3];
    #pragma unroll
    for (int i = 0; i < 9; ++i) { wq[i] = Wq[i]; wk[i] = Wk[i]; wv[i] = Wv[i]; }
    #pragma unroll
    for (int i = 0; i < 3; ++i) { bqv[i] = bq[i]; bkv[i] = bk[i]; bvv[i] = bv[i]; }

    float a[3][15], b[3][15], vv[3][15];

    stage45(q + (size_t)base * 45, buf, lane);
    WAITVM(0);
    projr<true>(buf + lane * 45, wq, bqv, a);
    WAITLG();
    stage45(k + (size_t)base * 45, buf, lane);
    WAITVM(0);
    projr<true>(buf + lane * 45, wk, bkv, b);
    WAITLG();
    stage45(v + (size_t)base * 45, buf, lane);
    WAITVM(0);
    projr<false>(buf + lane * 45, wv, bvv, vv);
    WAITLG();

    const float* dbase = dist + (size_t)base * 225;
    const int tok0 = lane / 15, j0 = lane - tok0 * 15;
    const int off0 = tok0 * 225 + j0;
    stage_row(dbase +  0, buf,       off0, j0);   // row0 -> S0  [vm 15]
    stage_row(dbase + 15, buf + 960, off0, j0);   // row1 -> S1  [vm 30]

    // ---- softmax + PV in registers (rows 0-1 in flight underneath) ----
    const float LOG2E = 1.4426950408889634f;
    #pragma unroll
    for (int h = 0; h < 3; ++h)
        #pragma unroll
        for (int n = 0; n < 15; ++n) a[h][n] *= LOG2E;

    float concat[45];                         // concat[n*3+h]
    #pragma unroll
    for (int h = 0; h < 3; ++h) {
        float amax = a[h][0], bmax = b[h][0];
        #pragma unroll
        for (int n = 1; n < 15; ++n) { amax = fmaxf(amax, a[h][n]); bmax = fmaxf(bmax, b[h][n]); }
        const float mm2 = amax * bmax;
        float zp[4] = {0.f, 0.f, 0.f, 0.f};   // 4-way partial sums: break the Z chain
        float pv[15];
        #pragma unroll
        for (int i = 0; i < 15; ++i) pv[i] = 0.f;
        #pragma unroll
        for (int i = 0; i < 15; ++i)
            #pragma unroll
            for (int j = 0; j < 15; ++j) {
                float t = EXP2F(fmaf(a[h][i], b[h][j], -mm2));
                zp[j & 3] += t;
                pv[i] = fmaf(t, vv[h][j], pv[i]);
            }
        const float rz = 1.f / ((zp[0] + zp[1]) + (zp[2] + zp[3]));
        #pragma unroll
        for (int i = 0; i < 15; ++i) concat[i*3 + h] = pv[i] * rz;
    }
    #pragma unroll
    for (int h = 0; h < 3; ++h)
        #pragma unroll
        for (int j = 0; j < 15; ++j) vv[h][j] *= 2.f;   // fold 2*distances into v

    // ---- 15 dist rows, ring-3, prefetch distance 2, counted vmcnt ----
    PHASE( 0, 15); PHASE( 1, 15); PHASE( 2, 15); PHASE( 3, 15);
    PHASE( 4, 15); PHASE( 5, 15); PHASE( 6, 15); PHASE( 7, 15);
    PHASE( 8, 15); PHASE( 9, 15); PHASE(10, 15); PHASE(11, 15);
    PHASE(12, 15); PHASE(13, 15); PHASE(14, 0);
    WAITLG();                                 // phase-14 ds_reads drained

    // ---- output projection: Wo/bo via uniform scalar loads ----
    #pragma unroll 3
    for (int o = 0; o < 45; ++o) {
        float acc = bo[o];
        const float* wr = Wo + o * 45;        // uniform address -> s_load
        #pragma unroll
        for (int cc = 0; cc < 45; ++cc) acc = fmaf(concat[cc], wr[cc], acc);
        buf[lane * 45 + o] = acc;
    }
    WAITLG();                                 // same-wave ds_writes drained
    {
        float4* o4 = (float4*)(out + (size_t)base * 45);
        const float4* s4 = (const float4*)buf;
        #pragma unroll
        for (int it = 0; it < 11; ++it) o4[it * 64 + lane] = s4[it * 64 + lane];
        if (lane < 16) o4[704 + lane] = s4[704 + lane];
    }
}

extern "C" void kernel_launch(void* const* d_in, const int* in_sizes, int n_in,
                              void* d_out, int out_size, void* d_ws, size_t ws_size,
                              hipStream_t stream) {
    const float* q  = (const float*)d_in[0];
    const float* k  = (const float*)d_in[1];
    const float* v  = (const float*)d_in[2];
    const float* ds = (const float*)d_in[3];
    const float* Wq = (const float*)d_in[5];
    const float* bq = (const float*)d_in[6];
    const float* Wk = (const float*)d_in[7];
    const float* bk = (const float*)d_in[8];
    const float* Wv = (const float*)d_in[9];
    const float* bv = (const float*)d_in[10];
    const float* Wo = (const float*)d_in[11];
    const float* bo = (const float*)d_in[12];
    float* out = (float*)d_out;

    // att_val = zeros(4096) at the tail of d_out
    hipMemsetAsync(out + (size_t)32 * 4096 * 45, 0, 4096 * sizeof(float), stream);

    mha_spatial_kernel<<<dim3((32 * 4096) / TOK), dim3(NT), 0, stream>>>(
        q, k, v, ds, Wq, bq, Wk, bk, Wv, bv, Wo, bo, out);
}